// Round 1
// baseline (1128.981 us; speedup 1.0000x reference)
//
#include <hip/hip_runtime.h>

#define HIST1_BINS 8320
#define KEY_CLAMP 0x40800000u

struct Ranks { unsigned int r[32]; };
struct Fracs { float f[16]; };

// ---------------- Kernel A: H2 + err + level-1 histogram (key >> 17) -------
__global__ __launch_bounds__(256) void k_h2(const float* __restrict__ logits,
                                            const int* __restrict__ labels,
                                            float* __restrict__ h2out,
                                            unsigned char* __restrict__ errout,
                                            unsigned int* __restrict__ hist1,
                                            int n) {
  __shared__ unsigned int lh[HIST1_BINS];
  for (int i = threadIdx.x; i < HIST1_BINS; i += blockDim.x) lh[i] = 0u;
  __syncthreads();
  int stride = gridDim.x * blockDim.x;
  for (int row = blockIdx.x * blockDim.x + threadIdx.x; row < n; row += stride) {
    const float4* rp = reinterpret_cast<const float4*>(logits) + (size_t)row * 4;
    float4 f0 = rp[0], f1 = rp[1], f2 = rp[2], f3 = rp[3];
    float l[16] = {f0.x, f0.y, f0.z, f0.w, f1.x, f1.y, f1.z, f1.w,
                   f2.x, f2.y, f2.z, f2.w, f3.x, f3.y, f3.z, f3.w};
    float m = l[0]; int am = 0;
#pragma unroll
    for (int j = 1; j < 16; ++j) { bool g = l[j] > m; m = g ? l[j] : m; am = g ? j : am; }
    float Z = 0.f, S2 = 0.f;
#pragma unroll
    for (int j = 0; j < 16; ++j) { float e = __expf(l[j] - m); Z += e; S2 += e * e; }
    float r = S2 / (Z * Z) + 1e-12f;
    float h2 = -__log2f(r);
    h2out[row] = h2;
    errout[row] = (unsigned char)((am != labels[row]) ? 1 : 0);
    unsigned int key = __float_as_uint(fmaxf(h2, 0.0f));
    key = key > KEY_CLAMP ? KEY_CLAMP : key;
    atomicAdd(&lh[key >> 17], 1u);
  }
  __syncthreads();
  for (int i = threadIdx.x; i < HIST1_BINS; i += blockDim.x) {
    unsigned int v = lh[i];
    if (v) atomicAdd(&hist1[i], v);
  }
}

// ---------------- Wave-cooperative rank selection on a histogram ----------
// One wave (64 lanes) per query j = blockIdx.x. Finds bucket containing rank
// `rem` in cumsum of h[0..nb), leaves remaining rank within bucket.
__global__ void k_select(const unsigned int* __restrict__ hist,
                         unsigned int* __restrict__ selpfx,
                         unsigned int* __restrict__ selrank,
                         float* __restrict__ vout,
                         int nb, int perq, int shift, int last, int first,
                         Ranks rk) {
  int j = blockIdx.x;
  int lane = threadIdx.x;
  const unsigned int* h = hist + (perq ? (size_t)j * (size_t)nb : (size_t)0);
  unsigned int rem = first ? rk.r[j] : selrank[j];
  int base = 0, len = nb;
  while (len > 64) {
    int chunk = (len + 63) >> 6;
    int start = base + lane * chunk;
    int end = base + len;
    unsigned int s = 0;
    for (int t = 0; t < chunk; ++t) {
      int idx = start + t;
      if (idx < end) s += h[idx];
    }
    unsigned int inc = s;
#pragma unroll
    for (int d = 1; d < 64; d <<= 1) {
      unsigned int u = __shfl_up(inc, d);
      if (lane >= d) inc += u;
    }
    unsigned int ex = inc - s;
    bool own = (rem >= ex) && (rem < ex + s);
    unsigned long long bal = __ballot(own);
    int src = __ffsll((long long)bal) - 1;
    unsigned int exs = __shfl(ex, src);
    int nbase = base + src * chunk;
    len = min(chunk, end - nbase);
    base = nbase;
    rem -= exs;
  }
  unsigned int s = (lane < len) ? h[base + lane] : 0u;
  unsigned int inc = s;
#pragma unroll
  for (int d = 1; d < 64; d <<= 1) {
    unsigned int u = __shfl_up(inc, d);
    if (lane >= d) inc += u;
  }
  unsigned int ex = inc - s;
  bool own = (rem >= ex) && (rem < ex + s);
  unsigned long long bal = __ballot(own);
  int src = __ffsll((long long)bal) - 1;
  unsigned int exs = __shfl(ex, src);
  if (lane == 0) {
    unsigned int idx = (unsigned int)(base + src);
    unsigned int pfx = first ? idx : ((selpfx[j] << shift) | idx);
    selpfx[j] = pfx;
    selrank[j] = rem - exs;
    if (last) vout[j] = __uint_as_float(pfx);
  }
}

// ---------------- Refine pass: sub-histogram for selected buckets ---------
__global__ __launch_bounds__(256) void k_refine(const float* __restrict__ h2arr,
                                                const unsigned int* __restrict__ selpfx,
                                                unsigned int* __restrict__ hist2,
                                                int n, int keyshift, int subshift,
                                                unsigned int submask, int nb) {
  __shared__ unsigned int sp[32];
  if (threadIdx.x < 32) sp[threadIdx.x] = selpfx[threadIdx.x];
  __syncthreads();
  int stride = gridDim.x * blockDim.x;
  for (int i = blockIdx.x * blockDim.x + threadIdx.x; i < n; i += stride) {
    unsigned int key = __float_as_uint(fmaxf(h2arr[i], 0.0f));
    key = key > KEY_CLAMP ? KEY_CLAMP : key;
    unsigned int hi = key >> keyshift;
    unsigned int sub = (key >> subshift) & submask;
#pragma unroll
    for (int jj = 0; jj < 32; ++jj) {
      if (hi == sp[jj]) atomicAdd(&hist2[jj * nb + (int)sub], 1u);
    }
  }
}

// ---------------- Edge interpolation --------------------------------------
__global__ void k_edges(const float* __restrict__ v, float* __restrict__ edges,
                        Fracs fr) {
  int i = threadIdx.x;
  if (i < 16) {
    float lo = v[2 * i], hi = v[2 * i + 1];
    float f = fr.f[i];
    float e = lo * (1.0f - f) + hi * f;
    if (i == 15) e += 1e-6f;
    edges[i] = e;
  }
}

// ---------------- Binning pass: per-bin cnt / sum(H2) / sum(err) ----------
__global__ __launch_bounds__(256) void k_bin(const float* __restrict__ h2arr,
                                             const unsigned char* __restrict__ errarr,
                                             const float* __restrict__ edges,
                                             float* __restrict__ acc, int n) {
  float e[16];
#pragma unroll
  for (int j = 0; j < 16; ++j) e[j] = edges[j];
  float cnt[15], sH[15], sE[15];
#pragma unroll
  for (int b = 0; b < 15; ++b) { cnt[b] = 0.f; sH[b] = 0.f; sE[b] = 0.f; }
  int stride = gridDim.x * blockDim.x;
  for (int i = blockIdx.x * blockDim.x + threadIdx.x; i < n; i += stride) {
    float h = h2arr[i];
    float er = (float)errarr[i];
    int less = 0;
#pragma unroll
    for (int j = 0; j < 16; ++j) less += (h > e[j]) ? 1 : 0;
    int bin = less - 1;  // valid bins 0..14; -1 (<=min) and 15 excluded
#pragma unroll
    for (int b = 0; b < 15; ++b) {
      bool m = (bin == b);
      cnt[b] += m ? 1.f : 0.f;
      sH[b] += m ? h : 0.f;
      sE[b] += m ? er : 0.f;
    }
  }
#pragma unroll
  for (int b = 0; b < 15; ++b) {
    float c = cnt[b], a = sH[b], s = sE[b];
    for (int off = 32; off > 0; off >>= 1) {
      c += __shfl_xor(c, off);
      a += __shfl_xor(a, off);
      s += __shfl_xor(s, off);
    }
    if ((threadIdx.x & 63) == 0) {
      atomicAdd(&acc[b], c);
      atomicAdd(&acc[15 + b], a);
      atomicAdd(&acc[30 + b], s);
    }
  }
}

// ---------------- Final: gaps mean ----------------------------------------
__global__ void k_final(const float* __restrict__ acc, float* __restrict__ out) {
  int l = threadIdx.x;
  float g = 0.f;
  if (l < 15) {
    float c = acc[l], sh = acc[15 + l], se = acc[30 + l];
    float safe = fmaxf(c, 1.f);
    float u = sh / safe, eb = se / safe;
    float inner = 2.0f * exp2f(-u) - 1.0f;
    float s = (inner > 0.f) ? sqrtf(inner) : 0.f;
    float risk = 0.5f * (1.0f - s);
    g = (c > 0.f) ? fabsf(eb - risk) : 0.f;
  }
  for (int off = 32; off > 0; off >>= 1) g += __shfl_xor(g, off);
  if (l == 0) out[0] = g * (1.0f / 15.0f);
}

extern "C" void kernel_launch(void* const* d_in, const int* in_sizes, int n_in,
                              void* d_out, int out_size, void* d_ws, size_t ws_size,
                              hipStream_t stream) {
  const float* logits = (const float*)d_in[0];
  const int* labels = (const int*)d_in[1];
  float* out = (float*)d_out;
  int n = in_sizes[1];  // labels count = number of rows

  char* ws = (char*)d_ws;
  size_t offH2 = 0;
  size_t offErr = (size_t)n * 4;
  size_t offCtrl = (offErr + (size_t)n + 255) & ~(size_t)255;
  size_t offH1 = offCtrl;                         // HIST1_BINS * 4
  size_t offH2a = offH1 + (size_t)HIST1_BINS * 4; // 32*512*4
  size_t offH2b = offH2a + 32 * 512 * 4;          // 32*256*4
  size_t offSelP = offH2b + 32 * 256 * 4;         // 32*4
  size_t offSelR = offSelP + 128;                 // 32*4
  size_t offV = offSelR + 128;                    // 32*4
  size_t offE = offV + 128;                       // 16*4
  size_t offAcc = offE + 64;                      // 45*4
  size_t ctrlEnd = offAcc + 180;

  float* h2p = (float*)(ws + offH2);
  unsigned char* errp = (unsigned char*)(ws + offErr);
  unsigned int* hist1 = (unsigned int*)(ws + offH1);
  unsigned int* h2a = (unsigned int*)(ws + offH2a);
  unsigned int* h2b = (unsigned int*)(ws + offH2b);
  unsigned int* selp = (unsigned int*)(ws + offSelP);
  unsigned int* selr = (unsigned int*)(ws + offSelR);
  float* vp = (float*)(ws + offV);
  float* edg = (float*)(ws + offE);
  float* acc = (float*)(ws + offAcc);

  // zero all histograms / selection state / accumulators (every call)
  hipMemsetAsync(ws + offCtrl, 0, ctrlEnd - offCtrl, stream);

  // host-side quantile positions, emulating f32 jnp.linspace / quantile index math
  Ranks rk;
  Fracs fr;
  float nm1 = (float)(n - 1);
  for (int i = 0; i < 16; ++i) {
    float q = (i == 15) ? 1.0f : (float)i * (1.0f / 15.0f);
    float idxf = q * nm1;
    float flo = floorf(idxf);
    unsigned int klo = (unsigned int)flo;
    unsigned int khi = (unsigned int)ceilf(idxf);
    unsigned int maxi = (unsigned int)(n - 1);
    if (klo > maxi) klo = maxi;
    if (khi > maxi) khi = maxi;
    rk.r[2 * i] = klo;
    rk.r[2 * i + 1] = khi;
    fr.f[i] = idxf - flo;
  }

  // 1) H2 + err + level-1 histogram
  k_h2<<<2048, 256, 0, stream>>>(logits, labels, h2p, errp, hist1, n);
  // 2) select level-1 bucket for each of 32 ranks
  k_select<<<32, 64, 0, stream>>>(hist1, selp, selr, vp, HIST1_BINS, 0, 0, 0, 1, rk);
  // 3) refine next 9 bits
  k_refine<<<1024, 256, 0, stream>>>(h2p, selp, h2a, n, 17, 8, 0x1FFu, 512);
  k_select<<<32, 64, 0, stream>>>(h2a, selp, selr, vp, 512, 1, 9, 0, 0, rk);
  // 4) refine last 8 bits -> exact key
  k_refine<<<1024, 256, 0, stream>>>(h2p, selp, h2b, n, 8, 0, 0xFFu, 256);
  k_select<<<32, 64, 0, stream>>>(h2b, selp, selr, vp, 256, 1, 8, 1, 0, rk);
  // 5) edges
  k_edges<<<1, 64, 0, stream>>>(vp, edg, fr);
  // 6) binning accumulation
  k_bin<<<1024, 256, 0, stream>>>(h2p, errp, edg, acc, n);
  // 7) final gaps mean
  k_final<<<1, 64, 0, stream>>>(acc, out);

  (void)n_in; (void)out_size; (void)ws_size;
}

// Round 2
// 352.170 us; speedup vs baseline: 3.2058x; 3.2058x over previous
//
#include <hip/hip_runtime.h>

#define HIST1_BINS 8320
#define KEY_CLAMP 0x40800000u
#define H1_REPL 16
#define NBIN_BLOCKS 256

struct Ranks { unsigned int r[32]; };
struct Fracs { float f[16]; };

// ---------------- Kernel A: H2 + err + level-1 histogram (key >> 17) -------
__global__ __launch_bounds__(256) void k_h2(const float* __restrict__ logits,
                                            const int* __restrict__ labels,
                                            float* __restrict__ h2out,
                                            unsigned char* __restrict__ errout,
                                            unsigned int* __restrict__ hist1,
                                            int n) {
  __shared__ unsigned int lh[HIST1_BINS];
  for (int i = threadIdx.x; i < HIST1_BINS; i += blockDim.x) lh[i] = 0u;
  __syncthreads();
  int stride = gridDim.x * blockDim.x;
  for (int row = blockIdx.x * blockDim.x + threadIdx.x; row < n; row += stride) {
    const float4* rp = reinterpret_cast<const float4*>(logits) + (size_t)row * 4;
    float4 f0 = rp[0], f1 = rp[1], f2 = rp[2], f3 = rp[3];
    float l[16] = {f0.x, f0.y, f0.z, f0.w, f1.x, f1.y, f1.z, f1.w,
                   f2.x, f2.y, f2.z, f2.w, f3.x, f3.y, f3.z, f3.w};
    float m = l[0]; int am = 0;
#pragma unroll
    for (int j = 1; j < 16; ++j) { bool g = l[j] > m; m = g ? l[j] : m; am = g ? j : am; }
    float Z = 0.f, S2 = 0.f;
#pragma unroll
    for (int j = 0; j < 16; ++j) { float e = __expf(l[j] - m); Z += e; S2 += e * e; }
    float r = S2 / (Z * Z) + 1e-12f;
    float h2 = -__log2f(r);
    h2out[row] = h2;
    errout[row] = (unsigned char)((am != labels[row]) ? 1 : 0);
    unsigned int key = __float_as_uint(fmaxf(h2, 0.0f));
    key = key > KEY_CLAMP ? KEY_CLAMP : key;
    atomicAdd(&lh[key >> 17], 1u);
  }
  __syncthreads();
  unsigned int rep = blockIdx.x & (H1_REPL - 1);
  for (int i = threadIdx.x; i < HIST1_BINS; i += blockDim.x) {
    unsigned int v = lh[i];
    if (v) atomicAdd(&hist1[rep * HIST1_BINS + i], v);
  }
}

// ---------------- Merge histogram replicas --------------------------------
__global__ void k_merge(const unsigned int* __restrict__ rep,
                        unsigned int* __restrict__ merged, int nb) {
  int i = blockIdx.x * blockDim.x + threadIdx.x;
  if (i < nb) {
    unsigned int s = 0;
#pragma unroll
    for (int r = 0; r < H1_REPL; ++r) s += rep[r * nb + i];
    merged[i] = s;
  }
}

// ---------------- Wave-cooperative rank selection on a histogram ----------
__global__ void k_select(const unsigned int* __restrict__ hist,
                         unsigned int* __restrict__ selpfx,
                         unsigned int* __restrict__ selrank,
                         float* __restrict__ vout,
                         int nb, int perq, int shift, int last, int first,
                         Ranks rk) {
  int j = blockIdx.x;
  int lane = threadIdx.x;
  const unsigned int* h = hist + (perq ? (size_t)j * (size_t)nb : (size_t)0);
  unsigned int rem = first ? rk.r[j] : selrank[j];
  int base = 0, len = nb;
  while (len > 64) {
    int chunk = (len + 63) >> 6;
    int start = base + lane * chunk;
    int end = base + len;
    unsigned int s = 0;
    for (int t = 0; t < chunk; ++t) {
      int idx = start + t;
      if (idx < end) s += h[idx];
    }
    unsigned int inc = s;
#pragma unroll
    for (int d = 1; d < 64; d <<= 1) {
      unsigned int u = __shfl_up(inc, d);
      if (lane >= d) inc += u;
    }
    unsigned int ex = inc - s;
    bool own = (rem >= ex) && (rem < ex + s);
    unsigned long long bal = __ballot(own);
    int src = __ffsll((long long)bal) - 1;
    unsigned int exs = __shfl(ex, src);
    int nbase = base + src * chunk;
    len = min(chunk, end - nbase);
    base = nbase;
    rem -= exs;
  }
  unsigned int s = (lane < len) ? h[base + lane] : 0u;
  unsigned int inc = s;
#pragma unroll
  for (int d = 1; d < 64; d <<= 1) {
    unsigned int u = __shfl_up(inc, d);
    if (lane >= d) inc += u;
  }
  unsigned int ex = inc - s;
  bool own = (rem >= ex) && (rem < ex + s);
  unsigned long long bal = __ballot(own);
  int src = __ffsll((long long)bal) - 1;
  unsigned int exs = __shfl(ex, src);
  if (lane == 0) {
    unsigned int idx = (unsigned int)(base + src);
    unsigned int pfx = first ? idx : ((selpfx[j] << shift) | idx);
    selpfx[j] = pfx;
    selrank[j] = rem - exs;
    if (last) vout[j] = __uint_as_float(pfx);
  }
}

// ---------------- Refine pass: sub-histogram for selected buckets ---------
__global__ __launch_bounds__(256) void k_refine(const float* __restrict__ h2arr,
                                                const unsigned int* __restrict__ selpfx,
                                                unsigned int* __restrict__ hist2,
                                                int n, int keyshift, int subshift,
                                                unsigned int submask, int nb) {
  __shared__ unsigned int sp[32];
  if (threadIdx.x < 32) sp[threadIdx.x] = selpfx[threadIdx.x];
  __syncthreads();
  int stride = gridDim.x * blockDim.x;
  for (int i = blockIdx.x * blockDim.x + threadIdx.x; i < n; i += stride) {
    unsigned int key = __float_as_uint(fmaxf(h2arr[i], 0.0f));
    key = key > KEY_CLAMP ? KEY_CLAMP : key;
    unsigned int hi = key >> keyshift;
    unsigned int sub = (key >> subshift) & submask;
#pragma unroll
    for (int jj = 0; jj < 32; ++jj) {
      if (hi == sp[jj]) atomicAdd(&hist2[jj * nb + (int)sub], 1u);
    }
  }
}

// ---------------- Edge interpolation --------------------------------------
__global__ void k_edges(const float* __restrict__ v, float* __restrict__ edges,
                        Fracs fr) {
  int i = threadIdx.x;
  if (i < 16) {
    float lo = v[2 * i], hi = v[2 * i + 1];
    float f = fr.f[i];
    float e = lo * (1.0f - f) + hi * f;
    if (i == 15) e += 1e-6f;
    edges[i] = e;
  }
}

// ---------------- Binning pass: per-block partials (no global atomics) ----
__global__ __launch_bounds__(256) void k_bin(const float* __restrict__ h2arr,
                                             const unsigned char* __restrict__ errarr,
                                             const float* __restrict__ edges,
                                             float* __restrict__ partials, int n) {
  __shared__ float swacc[4][48];
  float e[16];
#pragma unroll
  for (int j = 0; j < 16; ++j) e[j] = edges[j];
  float cnt[15], sH[15], sE[15];
#pragma unroll
  for (int b = 0; b < 15; ++b) { cnt[b] = 0.f; sH[b] = 0.f; sE[b] = 0.f; }
  int stride = gridDim.x * blockDim.x;
  for (int i = blockIdx.x * blockDim.x + threadIdx.x; i < n; i += stride) {
    float h = h2arr[i];
    float er = (float)errarr[i];
    int less = 0;
#pragma unroll
    for (int j = 0; j < 16; ++j) less += (h > e[j]) ? 1 : 0;
    int bin = less - 1;  // valid bins 0..14; -1 (<=min) and 15 excluded
#pragma unroll
    for (int b = 0; b < 15; ++b) {
      bool m = (bin == b);
      cnt[b] += m ? 1.f : 0.f;
      sH[b] += m ? h : 0.f;
      sE[b] += m ? er : 0.f;
    }
  }
  int wid = threadIdx.x >> 6;
  int lane = threadIdx.x & 63;
#pragma unroll
  for (int b = 0; b < 15; ++b) {
    float c = cnt[b], a = sH[b], s = sE[b];
    for (int off = 32; off > 0; off >>= 1) {
      c += __shfl_xor(c, off);
      a += __shfl_xor(a, off);
      s += __shfl_xor(s, off);
    }
    if (lane == 0) {
      swacc[wid][b] = c;
      swacc[wid][15 + b] = a;
      swacc[wid][30 + b] = s;
    }
  }
  __syncthreads();
  if (threadIdx.x < 45) {
    int v = threadIdx.x;
    float s = swacc[0][v] + swacc[1][v] + swacc[2][v] + swacc[3][v];
    partials[v * NBIN_BLOCKS + blockIdx.x] = s;
  }
}

// ---------------- Final: reduce partials, gaps mean -----------------------
__global__ void k_final(const float* __restrict__ partials, float* __restrict__ out) {
  __shared__ float sacc[45];
  int lane = threadIdx.x;  // 64 threads
  for (int v = 0; v < 45; ++v) {
    float s = 0.f;
    for (int b = lane; b < NBIN_BLOCKS; b += 64) s += partials[v * NBIN_BLOCKS + b];
    for (int off = 32; off > 0; off >>= 1) s += __shfl_xor(s, off);
    if (lane == 0) sacc[v] = s;
  }
  __syncthreads();
  float g = 0.f;
  if (lane < 15) {
    float c = sacc[lane], sh = sacc[15 + lane], se = sacc[30 + lane];
    float safe = fmaxf(c, 1.f);
    float u = sh / safe, eb = se / safe;
    float inner = 2.0f * exp2f(-u) - 1.0f;
    float s = (inner > 0.f) ? sqrtf(inner) : 0.f;
    float risk = 0.5f * (1.0f - s);
    g = (c > 0.f) ? fabsf(eb - risk) : 0.f;
  }
  for (int off = 32; off > 0; off >>= 1) g += __shfl_xor(g, off);
  if (lane == 0) out[0] = g * (1.0f / 15.0f);
}

extern "C" void kernel_launch(void* const* d_in, const int* in_sizes, int n_in,
                              void* d_out, int out_size, void* d_ws, size_t ws_size,
                              hipStream_t stream) {
  const float* logits = (const float*)d_in[0];
  const int* labels = (const int*)d_in[1];
  float* out = (float*)d_out;
  int n = in_sizes[1];  // labels count = number of rows

  char* ws = (char*)d_ws;
  size_t offH2 = 0;
  size_t offErr = (size_t)n * 4;
  size_t offCtrl = (offErr + (size_t)n + 255) & ~(size_t)255;
  size_t offH1 = offCtrl;                                   // H1_REPL * HIST1_BINS * 4
  size_t offH1m = offH1 + (size_t)H1_REPL * HIST1_BINS * 4; // HIST1_BINS * 4
  size_t offH2a = offH1m + (size_t)HIST1_BINS * 4;          // 32*512*4
  size_t offH2b = offH2a + 32 * 512 * 4;                    // 32*256*4
  size_t offSelP = offH2b + 32 * 256 * 4;                   // 32*4
  size_t offSelR = offSelP + 128;                           // 32*4
  size_t offV = offSelR + 128;                              // 32*4
  size_t offE = offV + 128;                                 // 16*4
  size_t ctrlEnd = offE + 64;
  size_t offPart = (ctrlEnd + 255) & ~(size_t)255;          // 45*NBIN_BLOCKS*4 (fully overwritten)

  float* h2p = (float*)(ws + offH2);
  unsigned char* errp = (unsigned char*)(ws + offErr);
  unsigned int* hist1 = (unsigned int*)(ws + offH1);
  unsigned int* hist1m = (unsigned int*)(ws + offH1m);
  unsigned int* h2a = (unsigned int*)(ws + offH2a);
  unsigned int* h2b = (unsigned int*)(ws + offH2b);
  unsigned int* selp = (unsigned int*)(ws + offSelP);
  unsigned int* selr = (unsigned int*)(ws + offSelR);
  float* vp = (float*)(ws + offV);
  float* edg = (float*)(ws + offE);
  float* part = (float*)(ws + offPart);

  // zero all histograms / selection state (every call)
  hipMemsetAsync(ws + offCtrl, 0, ctrlEnd - offCtrl, stream);

  // host-side quantile positions, emulating f32 jnp.linspace / quantile index math
  Ranks rk;
  Fracs fr;
  float nm1 = (float)(n - 1);
  for (int i = 0; i < 16; ++i) {
    float q = (i == 15) ? 1.0f : (float)i * (1.0f / 15.0f);
    float idxf = q * nm1;
    float flo = floorf(idxf);
    unsigned int klo = (unsigned int)flo;
    unsigned int khi = (unsigned int)ceilf(idxf);
    unsigned int maxi = (unsigned int)(n - 1);
    if (klo > maxi) klo = maxi;
    if (khi > maxi) khi = maxi;
    rk.r[2 * i] = klo;
    rk.r[2 * i + 1] = khi;
    fr.f[i] = idxf - flo;
  }

  // 1) H2 + err + level-1 histogram (16 replicas)
  k_h2<<<1024, 256, 0, stream>>>(logits, labels, h2p, errp, hist1, n);
  k_merge<<<(HIST1_BINS + 255) / 256, 256, 0, stream>>>(hist1, hist1m, HIST1_BINS);
  // 2) select level-1 bucket for each of 32 ranks
  k_select<<<32, 64, 0, stream>>>(hist1m, selp, selr, vp, HIST1_BINS, 0, 0, 0, 1, rk);
  // 3) refine next 9 bits
  k_refine<<<1024, 256, 0, stream>>>(h2p, selp, h2a, n, 17, 8, 0x1FFu, 512);
  k_select<<<32, 64, 0, stream>>>(h2a, selp, selr, vp, 512, 1, 9, 0, 0, rk);
  // 4) refine last 8 bits -> exact key
  k_refine<<<1024, 256, 0, stream>>>(h2p, selp, h2b, n, 8, 0, 0xFFu, 256);
  k_select<<<32, 64, 0, stream>>>(h2b, selp, selr, vp, 256, 1, 8, 1, 0, rk);
  // 5) edges
  k_edges<<<1, 64, 0, stream>>>(vp, edg, fr);
  // 6) binning accumulation (block partials, no global atomics)
  k_bin<<<NBIN_BLOCKS, 256, 0, stream>>>(h2p, errp, edg, part, n);
  // 7) final reduce + gaps mean
  k_final<<<1, 64, 0, stream>>>(part, out);

  (void)n_in; (void)out_size; (void)ws_size;
}

// Round 3
// 351.947 us; speedup vs baseline: 3.2078x; 1.0006x over previous
//
#include <hip/hip_runtime.h>

#define HIST1_BINS 8320
#define KEY_CLAMP 0x40800000u
#define H1_REPL 16
#define NBIN_BLOCKS 256

struct Ranks { unsigned int r[32]; };
struct Fracs { float f[16]; };

// ---------------- Zero the control region (replaces hipMemsetAsync) -------
__global__ __launch_bounds__(256) void k_zero(uint4* __restrict__ p, int n4) {
  int stride = gridDim.x * blockDim.x;
  for (int i = blockIdx.x * blockDim.x + threadIdx.x; i < n4; i += stride)
    p[i] = make_uint4(0u, 0u, 0u, 0u);
}

// ---------------- Kernel A: H2 + err + level-1 histogram (key >> 17) -------
// LDS histogram packs 2 replicas per uint (lo/hi halfword by wave parity);
// per-block per-half counts <= 4096 so no cross-half carry.
__global__ __launch_bounds__(256) void k_h2(const float* __restrict__ logits,
                                            const int* __restrict__ labels,
                                            float* __restrict__ h2out,
                                            unsigned char* __restrict__ errout,
                                            unsigned int* __restrict__ hist1,
                                            int n) {
  __shared__ unsigned int lh[HIST1_BINS];
  for (int i = threadIdx.x; i < HIST1_BINS; i += blockDim.x) lh[i] = 0u;
  __syncthreads();
  unsigned int addend = (threadIdx.x & 64) ? 65536u : 1u;
  int stride = gridDim.x * blockDim.x;
  for (int row = blockIdx.x * blockDim.x + threadIdx.x; row < n; row += stride) {
    const float4* rp = reinterpret_cast<const float4*>(logits) + (size_t)row * 4;
    float4 f0 = rp[0], f1 = rp[1], f2 = rp[2], f3 = rp[3];
    float l[16] = {f0.x, f0.y, f0.z, f0.w, f1.x, f1.y, f1.z, f1.w,
                   f2.x, f2.y, f2.z, f2.w, f3.x, f3.y, f3.z, f3.w};
    float m = l[0]; int am = 0;
#pragma unroll
    for (int j = 1; j < 16; ++j) { bool g = l[j] > m; m = g ? l[j] : m; am = g ? j : am; }
    float Z = 0.f, S2 = 0.f;
#pragma unroll
    for (int j = 0; j < 16; ++j) { float e = __expf(l[j] - m); Z += e; S2 += e * e; }
    float r = S2 / (Z * Z) + 1e-12f;
    float h2 = -__log2f(r);
    h2out[row] = h2;
    errout[row] = (unsigned char)((am != labels[row]) ? 1 : 0);
    unsigned int key = __float_as_uint(fmaxf(h2, 0.0f));
    key = key > KEY_CLAMP ? KEY_CLAMP : key;
    atomicAdd(&lh[key >> 17], addend);
  }
  __syncthreads();
  unsigned int rep = blockIdx.x & (H1_REPL - 1);
  for (int i = threadIdx.x; i < HIST1_BINS; i += blockDim.x) {
    unsigned int v = lh[i];
    unsigned int cnt = (v & 0xFFFFu) + (v >> 16);
    if (cnt) atomicAdd(&hist1[rep * HIST1_BINS + i], cnt);
  }
}

// ---------------- Merge histogram replicas --------------------------------
__global__ void k_merge(const unsigned int* __restrict__ rep,
                        unsigned int* __restrict__ merged, int nb) {
  int i = blockIdx.x * blockDim.x + threadIdx.x;
  if (i < nb) {
    unsigned int s = 0;
#pragma unroll
    for (int r = 0; r < H1_REPL; ++r) s += rep[r * nb + i];
    merged[i] = s;
  }
}

// ---------------- Wave-cooperative rank selection on a histogram ----------
__global__ void k_select(const unsigned int* __restrict__ hist,
                         unsigned int* __restrict__ selpfx,
                         unsigned int* __restrict__ selrank,
                         float* __restrict__ vout,
                         int nb, int perq, int shift, int last, int first,
                         Ranks rk) {
  int j = blockIdx.x;
  int lane = threadIdx.x;
  const unsigned int* h = hist + (perq ? (size_t)j * (size_t)nb : (size_t)0);
  unsigned int rem = first ? rk.r[j] : selrank[j];
  int base = 0, len = nb;
  while (len > 64) {
    int chunk = (len + 63) >> 6;
    int start = base + lane * chunk;
    int end = base + len;
    unsigned int s = 0;
    for (int t = 0; t < chunk; ++t) {
      int idx = start + t;
      if (idx < end) s += h[idx];
    }
    unsigned int inc = s;
#pragma unroll
    for (int d = 1; d < 64; d <<= 1) {
      unsigned int u = __shfl_up(inc, d);
      if (lane >= d) inc += u;
    }
    unsigned int ex = inc - s;
    bool own = (rem >= ex) && (rem < ex + s);
    unsigned long long bal = __ballot(own);
    int src = __ffsll((long long)bal) - 1;
    unsigned int exs = __shfl(ex, src);
    int nbase = base + src * chunk;
    len = min(chunk, end - nbase);
    base = nbase;
    rem -= exs;
  }
  unsigned int s = (lane < len) ? h[base + lane] : 0u;
  unsigned int inc = s;
#pragma unroll
  for (int d = 1; d < 64; d <<= 1) {
    unsigned int u = __shfl_up(inc, d);
    if (lane >= d) inc += u;
  }
  unsigned int ex = inc - s;
  bool own = (rem >= ex) && (rem < ex + s);
  unsigned long long bal = __ballot(own);
  int src = __ffsll((long long)bal) - 1;
  unsigned int exs = __shfl(ex, src);
  if (lane == 0) {
    unsigned int idx = (unsigned int)(base + src);
    unsigned int pfx = first ? idx : ((selpfx[j] << shift) | idx);
    selpfx[j] = pfx;
    selrank[j] = rem - exs;
    if (last) vout[j] = __uint_as_float(pfx);
  }
}

// ---------------- Refine pass: sub-histogram for selected buckets ---------
__global__ __launch_bounds__(256) void k_refine(const float* __restrict__ h2arr,
                                                const unsigned int* __restrict__ selpfx,
                                                unsigned int* __restrict__ hist2,
                                                int n, int keyshift, int subshift,
                                                unsigned int submask, int nb) {
  __shared__ unsigned int sp[32];
  if (threadIdx.x < 32) sp[threadIdx.x] = selpfx[threadIdx.x];
  __syncthreads();
  int stride = gridDim.x * blockDim.x;
  for (int i = blockIdx.x * blockDim.x + threadIdx.x; i < n; i += stride) {
    unsigned int key = __float_as_uint(fmaxf(h2arr[i], 0.0f));
    key = key > KEY_CLAMP ? KEY_CLAMP : key;
    unsigned int hi = key >> keyshift;
    unsigned int sub = (key >> subshift) & submask;
#pragma unroll
    for (int jj = 0; jj < 32; ++jj) {
      if (hi == sp[jj]) atomicAdd(&hist2[jj * nb + (int)sub], 1u);
    }
  }
}

// ---------------- Edge interpolation --------------------------------------
__global__ void k_edges(const float* __restrict__ v, float* __restrict__ edges,
                        Fracs fr) {
  int i = threadIdx.x;
  if (i < 16) {
    float lo = v[2 * i], hi = v[2 * i + 1];
    float f = fr.f[i];
    float e = lo * (1.0f - f) + hi * f;
    if (i == 15) e += 1e-6f;
    edges[i] = e;
  }
}

// ---------------- Binning pass: per-block partials (no global atomics) ----
__global__ __launch_bounds__(256) void k_bin(const float* __restrict__ h2arr,
                                             const unsigned char* __restrict__ errarr,
                                             const float* __restrict__ edges,
                                             float* __restrict__ partials, int n) {
  __shared__ float swacc[4][48];
  float e[16];
#pragma unroll
  for (int j = 0; j < 16; ++j) e[j] = edges[j];
  float cnt[15], sH[15], sE[15];
#pragma unroll
  for (int b = 0; b < 15; ++b) { cnt[b] = 0.f; sH[b] = 0.f; sE[b] = 0.f; }
  int stride = gridDim.x * blockDim.x;
  for (int i = blockIdx.x * blockDim.x + threadIdx.x; i < n; i += stride) {
    float h = h2arr[i];
    float er = (float)errarr[i];
    int less = 0;
#pragma unroll
    for (int j = 0; j < 16; ++j) less += (h > e[j]) ? 1 : 0;
    int bin = less - 1;  // valid bins 0..14; -1 (<=min) and 15 excluded
#pragma unroll
    for (int b = 0; b < 15; ++b) {
      bool m = (bin == b);
      cnt[b] += m ? 1.f : 0.f;
      sH[b] += m ? h : 0.f;
      sE[b] += m ? er : 0.f;
    }
  }
  int wid = threadIdx.x >> 6;
  int lane = threadIdx.x & 63;
#pragma unroll
  for (int b = 0; b < 15; ++b) {
    float c = cnt[b], a = sH[b], s = sE[b];
    for (int off = 32; off > 0; off >>= 1) {
      c += __shfl_xor(c, off);
      a += __shfl_xor(a, off);
      s += __shfl_xor(s, off);
    }
    if (lane == 0) {
      swacc[wid][b] = c;
      swacc[wid][15 + b] = a;
      swacc[wid][30 + b] = s;
    }
  }
  __syncthreads();
  if (threadIdx.x < 45) {
    int v = threadIdx.x;
    float s = swacc[0][v] + swacc[1][v] + swacc[2][v] + swacc[3][v];
    partials[v * NBIN_BLOCKS + blockIdx.x] = s;
  }
}

// ---------------- Final: reduce partials, gaps mean -----------------------
__global__ void k_final(const float* __restrict__ partials, float* __restrict__ out) {
  __shared__ float sacc[45];
  int lane = threadIdx.x;  // 64 threads
  for (int v = 0; v < 45; ++v) {
    float s = 0.f;
    for (int b = lane; b < NBIN_BLOCKS; b += 64) s += partials[v * NBIN_BLOCKS + b];
    for (int off = 32; off > 0; off >>= 1) s += __shfl_xor(s, off);
    if (lane == 0) sacc[v] = s;
  }
  __syncthreads();
  float g = 0.f;
  if (lane < 15) {
    float c = sacc[lane], sh = sacc[15 + lane], se = sacc[30 + lane];
    float safe = fmaxf(c, 1.f);
    float u = sh / safe, eb = se / safe;
    float inner = 2.0f * exp2f(-u) - 1.0f;
    float s = (inner > 0.f) ? sqrtf(inner) : 0.f;
    float risk = 0.5f * (1.0f - s);
    g = (c > 0.f) ? fabsf(eb - risk) : 0.f;
  }
  for (int off = 32; off > 0; off >>= 1) g += __shfl_xor(g, off);
  if (lane == 0) out[0] = g * (1.0f / 15.0f);
}

extern "C" void kernel_launch(void* const* d_in, const int* in_sizes, int n_in,
                              void* d_out, int out_size, void* d_ws, size_t ws_size,
                              hipStream_t stream) {
  const float* logits = (const float*)d_in[0];
  const int* labels = (const int*)d_in[1];
  float* out = (float*)d_out;
  int n = in_sizes[1];  // labels count = number of rows

  char* ws = (char*)d_ws;
  size_t offH2 = 0;
  size_t offErr = (size_t)n * 4;
  size_t offCtrl = (offErr + (size_t)n + 255) & ~(size_t)255;
  size_t offH1 = offCtrl;                                   // H1_REPL * HIST1_BINS * 4
  size_t offH1m = offH1 + (size_t)H1_REPL * HIST1_BINS * 4; // HIST1_BINS * 4
  size_t offH2a = offH1m + (size_t)HIST1_BINS * 4;          // 32*512*4
  size_t offH2b = offH2a + 32 * 512 * 4;                    // 32*256*4
  size_t offSelP = offH2b + 32 * 256 * 4;                   // 32*4
  size_t offSelR = offSelP + 128;                           // 32*4
  size_t offV = offSelR + 128;                              // 32*4
  size_t offE = offV + 128;                                 // 16*4
  size_t ctrlEnd = offE + 64;
  size_t offPart = (ctrlEnd + 255) & ~(size_t)255;          // 45*NBIN_BLOCKS*4 (fully overwritten)

  float* h2p = (float*)(ws + offH2);
  unsigned char* errp = (unsigned char*)(ws + offErr);
  unsigned int* hist1 = (unsigned int*)(ws + offH1);
  unsigned int* hist1m = (unsigned int*)(ws + offH1m);
  unsigned int* h2a = (unsigned int*)(ws + offH2a);
  unsigned int* h2b = (unsigned int*)(ws + offH2b);
  unsigned int* selp = (unsigned int*)(ws + offSelP);
  unsigned int* selr = (unsigned int*)(ws + offSelR);
  float* vp = (float*)(ws + offV);
  float* edg = (float*)(ws + offE);
  float* part = (float*)(ws + offPart);

  // zero all histograms / selection state with our own kernel (the graph-
  // captured hipMemsetAsync fill node cost ~155us; plain stores are ~2us)
  int zero4 = (int)((ctrlEnd - offCtrl) >> 4);  // region is 16B-aligned/sized
  k_zero<<<(zero4 + 255) / 256, 256, 0, stream>>>((uint4*)(ws + offCtrl), zero4);

  // host-side quantile positions, emulating f32 jnp.linspace / quantile index math
  Ranks rk;
  Fracs fr;
  float nm1 = (float)(n - 1);
  for (int i = 0; i < 16; ++i) {
    float q = (i == 15) ? 1.0f : (float)i * (1.0f / 15.0f);
    float idxf = q * nm1;
    float flo = floorf(idxf);
    unsigned int klo = (unsigned int)flo;
    unsigned int khi = (unsigned int)ceilf(idxf);
    unsigned int maxi = (unsigned int)(n - 1);
    if (klo > maxi) klo = maxi;
    if (khi > maxi) khi = maxi;
    rk.r[2 * i] = klo;
    rk.r[2 * i + 1] = khi;
    fr.f[i] = idxf - flo;
  }

  // 1) H2 + err + level-1 histogram (16 replicas, dual-packed LDS)
  k_h2<<<1024, 256, 0, stream>>>(logits, labels, h2p, errp, hist1, n);
  k_merge<<<(HIST1_BINS + 255) / 256, 256, 0, stream>>>(hist1, hist1m, HIST1_BINS);
  // 2) select level-1 bucket for each of 32 ranks
  k_select<<<32, 64, 0, stream>>>(hist1m, selp, selr, vp, HIST1_BINS, 0, 0, 0, 1, rk);
  // 3) refine next 9 bits
  k_refine<<<1024, 256, 0, stream>>>(h2p, selp, h2a, n, 17, 8, 0x1FFu, 512);
  k_select<<<32, 64, 0, stream>>>(h2a, selp, selr, vp, 512, 1, 9, 0, 0, rk);
  // 4) refine last 8 bits -> exact key
  k_refine<<<1024, 256, 0, stream>>>(h2p, selp, h2b, n, 8, 0, 0xFFu, 256);
  k_select<<<32, 64, 0, stream>>>(h2b, selp, selr, vp, 256, 1, 8, 1, 0, rk);
  // 5) edges
  k_edges<<<1, 64, 0, stream>>>(vp, edg, fr);
  // 6) binning accumulation (block partials, no global atomics)
  k_bin<<<NBIN_BLOCKS, 256, 0, stream>>>(h2p, errp, edg, part, n);
  // 7) final reduce + gaps mean
  k_final<<<1, 64, 0, stream>>>(part, out);

  (void)n_in; (void)out_size; (void)ws_size;
}

// Round 4
// 323.062 us; speedup vs baseline: 3.4946x; 1.0894x over previous
//
#include <hip/hip_runtime.h>

#define L1_BINS 8192          // top 13 bits of 22-bit fixed-point key
#define L2_BINS 512           // low 9 bits
#define KEY_MAX 4194303u      // 2^22 - 1
#define NH2_BLOCKS 1024
#define NBIN_BLOCKS 256

struct Ranks { unsigned int r[32]; };
struct Fracs { float f[16]; };

// ---------------- Zero hist2 (replaces hipMemsetAsync) --------------------
__global__ __launch_bounds__(256) void k_zero(uint4* __restrict__ p, int n4) {
  int i = blockIdx.x * blockDim.x + threadIdx.x;
  if (i < n4) p[i] = make_uint4(0u, 0u, 0u, 0u);
}

// ---------------- Kernel A: H2/err -> packed key + per-block L1 hist ------
// key = clamp((int)(h2 * 2^20), 0, 2^22-1); packed = key | err<<31.
// Per-block hist flushed with PLAIN stores (pairs packed in uint), no atomics.
__global__ __launch_bounds__(256) void k_h2(const float* __restrict__ logits,
                                            const int* __restrict__ labels,
                                            unsigned int* __restrict__ keys,
                                            unsigned int* __restrict__ histg,
                                            int n) {
  __shared__ unsigned int lh[L1_BINS];
  for (int i = threadIdx.x; i < L1_BINS; i += blockDim.x) lh[i] = 0u;
  __syncthreads();
  int stride = gridDim.x * blockDim.x;
  for (int row = blockIdx.x * blockDim.x + threadIdx.x; row < n; row += stride) {
    const float4* rp = reinterpret_cast<const float4*>(logits) + (size_t)row * 4;
    float4 f0 = rp[0], f1 = rp[1], f2 = rp[2], f3 = rp[3];
    float l[16] = {f0.x, f0.y, f0.z, f0.w, f1.x, f1.y, f1.z, f1.w,
                   f2.x, f2.y, f2.z, f2.w, f3.x, f3.y, f3.z, f3.w};
    float m = l[0]; int am = 0;
#pragma unroll
    for (int j = 1; j < 16; ++j) { bool g = l[j] > m; m = g ? l[j] : m; am = g ? j : am; }
    float Z = 0.f, S2 = 0.f;
#pragma unroll
    for (int j = 0; j < 16; ++j) { float e = __expf(l[j] - m); Z += e; S2 += e * e; }
    float r = S2 / (Z * Z) + 1e-12f;
    float h2 = -__log2f(r);
    int ki = (int)(h2 * 1048576.0f);           // 2^20 per unit, trunc like ref order
    unsigned int key = (unsigned int)min(max(ki, 0), (int)KEY_MAX);
    unsigned int err = (am != labels[row]) ? 0x80000000u : 0u;
    keys[row] = key | err;
    atomicAdd(&lh[key >> 9], 1u);
  }
  __syncthreads();
  // plain coalesced flush: pack two adjacent bins per uint (counts <= 4096)
  unsigned int* dst = histg + (size_t)blockIdx.x * (L1_BINS / 2);
  for (int i = threadIdx.x; i < L1_BINS / 2; i += blockDim.x)
    dst[i] = (lh[2 * i] & 0xFFFFu) | (lh[2 * i + 1] << 16);
}

// ---------------- Merge per-block hists -> merged[L1_BINS] ----------------
__global__ __launch_bounds__(256) void k_merge(const unsigned int* __restrict__ histg,
                                               unsigned int* __restrict__ merged,
                                               int nblocks) {
  int i = blockIdx.x * blockDim.x + threadIdx.x;  // pair index [0, L1_BINS/2)
  if (i < L1_BINS / 2) {
    unsigned int slo = 0, shi = 0;
    for (int b = 0; b < nblocks; ++b) {
      unsigned int v = histg[(size_t)b * (L1_BINS / 2) + i];
      slo += v & 0xFFFFu;
      shi += v >> 16;
    }
    merged[2 * i] = slo;
    merged[2 * i + 1] = shi;
  }
}

// ---------------- Wave-cooperative rank selection on a histogram ----------
__global__ void k_select(const unsigned int* __restrict__ hist,
                         unsigned int* __restrict__ selpfx,
                         unsigned int* __restrict__ selrank,
                         float* __restrict__ vout,
                         int nb, int perq, int shift, int last, int first,
                         Ranks rk) {
  int j = blockIdx.x;
  int lane = threadIdx.x;
  const unsigned int* h = hist + (perq ? (size_t)j * (size_t)nb : (size_t)0);
  unsigned int rem = first ? rk.r[j] : selrank[j];
  int base = 0, len = nb;
  while (len > 64) {
    int chunk = (len + 63) >> 6;
    int start = base + lane * chunk;
    int end = base + len;
    unsigned int s = 0;
    for (int t = 0; t < chunk; ++t) {
      int idx = start + t;
      if (idx < end) s += h[idx];
    }
    unsigned int inc = s;
#pragma unroll
    for (int d = 1; d < 64; d <<= 1) {
      unsigned int u = __shfl_up(inc, d);
      if (lane >= d) inc += u;
    }
    unsigned int ex = inc - s;
    bool own = (rem >= ex) && (rem < ex + s);
    unsigned long long bal = __ballot(own);
    int src = __ffsll((long long)bal) - 1;
    unsigned int exs = __shfl(ex, src);
    int nbase = base + src * chunk;
    len = min(chunk, end - nbase);
    base = nbase;
    rem -= exs;
  }
  unsigned int s = (lane < len) ? h[base + lane] : 0u;
  unsigned int inc = s;
#pragma unroll
  for (int d = 1; d < 64; d <<= 1) {
    unsigned int u = __shfl_up(inc, d);
    if (lane >= d) inc += u;
  }
  unsigned int ex = inc - s;
  bool own = (rem >= ex) && (rem < ex + s);
  unsigned long long bal = __ballot(own);
  int src = __ffsll((long long)bal) - 1;
  unsigned int exs = __shfl(ex, src);
  if (lane == 0) {
    unsigned int idx = (unsigned int)(base + src);
    unsigned int pfx = first ? idx : ((selpfx[j] << shift) | idx);
    selpfx[j] = pfx;
    selrank[j] = rem - exs;
    if (last) vout[j] = __uint_as_float(pfx);  // final 22-bit key
  }
}

// ---------------- Refine: sub-hist (low 9 bits) for selected L1 buckets ---
__global__ __launch_bounds__(256) void k_refine(const unsigned int* __restrict__ keys,
                                                const unsigned int* __restrict__ selpfx,
                                                unsigned int* __restrict__ hist2,
                                                int n) {
  __shared__ unsigned int sp[32];
  if (threadIdx.x < 32) sp[threadIdx.x] = selpfx[threadIdx.x];
  __syncthreads();
  int stride = gridDim.x * blockDim.x;
  for (int i = blockIdx.x * blockDim.x + threadIdx.x; i < n; i += stride) {
    unsigned int key = keys[i] & KEY_MAX;
    unsigned int hi = key >> 9;
    unsigned int sub = key & (L2_BINS - 1);
#pragma unroll
    for (int jj = 0; jj < 32; ++jj) {
      if (hi == sp[jj]) atomicAdd(&hist2[jj * L2_BINS + (int)sub], 1u);
    }
  }
}

// ---------------- Binning pass: per-block partials (no global atomics) ----
// Edges computed per block from final keys (value = (key+1)*2^-20, exact).
__global__ __launch_bounds__(256) void k_bin(const unsigned int* __restrict__ keys,
                                             const float* __restrict__ vp,
                                             float* __restrict__ partials, int n,
                                             Fracs fr) {
  __shared__ float sedge[16];
  __shared__ float swacc[4][48];
  if (threadIdx.x < 16) {
    int i = threadIdx.x;
    unsigned int klo = __float_as_uint(vp[2 * i]);
    unsigned int khi = __float_as_uint(vp[2 * i + 1]);
    float lo = (float)(klo + 1u) * 0x1p-20f;   // upper boundary of bin (exact)
    float hi = (float)(khi + 1u) * 0x1p-20f;
    float f = fr.f[i];
    float e = lo * (1.0f - f) + hi * f;
    if (i == 15) e += 1e-6f;
    sedge[i] = e;
  }
  __syncthreads();
  float e[16];
#pragma unroll
  for (int j = 0; j < 16; ++j) e[j] = sedge[j];
  float cnt[15], sH[15], sE[15];
#pragma unroll
  for (int b = 0; b < 15; ++b) { cnt[b] = 0.f; sH[b] = 0.f; sE[b] = 0.f; }
  int stride = gridDim.x * blockDim.x;
  for (int i = blockIdx.x * blockDim.x + threadIdx.x; i < n; i += stride) {
    unsigned int kp = keys[i];
    float h = ((float)(kp & KEY_MAX) + 0.5f) * 0x1p-20f;
    float er = (kp & 0x80000000u) ? 1.0f : 0.0f;
    int less = 0;
#pragma unroll
    for (int j = 0; j < 16; ++j) less += (h > e[j]) ? 1 : 0;
    int bin = less - 1;  // valid bins 0..14
#pragma unroll
    for (int b = 0; b < 15; ++b) {
      bool m = (bin == b);
      cnt[b] += m ? 1.f : 0.f;
      sH[b] += m ? h : 0.f;
      sE[b] += m ? er : 0.f;
    }
  }
  int wid = threadIdx.x >> 6;
  int lane = threadIdx.x & 63;
#pragma unroll
  for (int b = 0; b < 15; ++b) {
    float c = cnt[b], a = sH[b], s = sE[b];
    for (int off = 32; off > 0; off >>= 1) {
      c += __shfl_xor(c, off);
      a += __shfl_xor(a, off);
      s += __shfl_xor(s, off);
    }
    if (lane == 0) {
      swacc[wid][b] = c;
      swacc[wid][15 + b] = a;
      swacc[wid][30 + b] = s;
    }
  }
  __syncthreads();
  if (threadIdx.x < 45) {
    int v = threadIdx.x;
    float s = swacc[0][v] + swacc[1][v] + swacc[2][v] + swacc[3][v];
    partials[v * NBIN_BLOCKS + blockIdx.x] = s;
  }
}

// ---------------- Final: reduce partials, gaps mean -----------------------
__global__ void k_final(const float* __restrict__ partials, float* __restrict__ out) {
  __shared__ float sacc[45];
  int lane = threadIdx.x;  // 64 threads
  for (int v = 0; v < 45; ++v) {
    float s = 0.f;
    for (int b = lane; b < NBIN_BLOCKS; b += 64) s += partials[v * NBIN_BLOCKS + b];
    for (int off = 32; off > 0; off >>= 1) s += __shfl_xor(s, off);
    if (lane == 0) sacc[v] = s;
  }
  __syncthreads();
  float g = 0.f;
  if (lane < 15) {
    float c = sacc[lane], sh = sacc[15 + lane], se = sacc[30 + lane];
    float safe = fmaxf(c, 1.f);
    float u = sh / safe, eb = se / safe;
    float inner = 2.0f * exp2f(-u) - 1.0f;
    float s = (inner > 0.f) ? sqrtf(inner) : 0.f;
    float risk = 0.5f * (1.0f - s);
    g = (c > 0.f) ? fabsf(eb - risk) : 0.f;
  }
  for (int off = 32; off > 0; off >>= 1) g += __shfl_xor(g, off);
  if (lane == 0) out[0] = g * (1.0f / 15.0f);
}

extern "C" void kernel_launch(void* const* d_in, const int* in_sizes, int n_in,
                              void* d_out, int out_size, void* d_ws, size_t ws_size,
                              hipStream_t stream) {
  const float* logits = (const float*)d_in[0];
  const int* labels = (const int*)d_in[1];
  float* out = (float*)d_out;
  int n = in_sizes[1];  // labels count = number of rows

  char* ws = (char*)d_ws;
  size_t offKeys = 0;                                         // n*4
  size_t offHg = (size_t)n * 4;                               // 1024 * 4096 * 4 = 16MB
  size_t offMerged = offHg + (size_t)NH2_BLOCKS * (L1_BINS / 2) * 4;  // 8192*4
  size_t offH2b = offMerged + (size_t)L1_BINS * 4;            // 32*512*4 = 64KB (zeroed)
  size_t offSelP = offH2b + 32 * L2_BINS * 4;                 // 32*4
  size_t offSelR = offSelP + 128;                             // 32*4
  size_t offV = offSelR + 128;                                // 32*4
  size_t offPart = (offV + 128 + 255) & ~(size_t)255;         // 45*NBIN_BLOCKS*4

  unsigned int* keys = (unsigned int*)(ws + offKeys);
  unsigned int* histg = (unsigned int*)(ws + offHg);
  unsigned int* merged = (unsigned int*)(ws + offMerged);
  unsigned int* hist2 = (unsigned int*)(ws + offH2b);
  unsigned int* selp = (unsigned int*)(ws + offSelP);
  unsigned int* selr = (unsigned int*)(ws + offSelR);
  float* vp = (float*)(ws + offV);
  float* part = (float*)(ws + offPart);

  // host-side quantile positions, emulating f32 jnp.linspace / quantile index math
  Ranks rk;
  Fracs fr;
  float nm1 = (float)(n - 1);
  for (int i = 0; i < 16; ++i) {
    float q = (i == 15) ? 1.0f : (float)i * (1.0f / 15.0f);
    float idxf = q * nm1;
    float flo = floorf(idxf);
    unsigned int klo = (unsigned int)flo;
    unsigned int khi = (unsigned int)ceilf(idxf);
    unsigned int maxi = (unsigned int)(n - 1);
    if (klo > maxi) klo = maxi;
    if (khi > maxi) khi = maxi;
    rk.r[2 * i] = klo;
    rk.r[2 * i + 1] = khi;
    fr.f[i] = idxf - flo;
  }

  // 0) zero hist2 (64KB)
  k_zero<<<16, 256, 0, stream>>>((uint4*)(ws + offH2b), 32 * L2_BINS / 4);
  // 1) H2 -> packed keys + per-block L1 hists (plain stores)
  k_h2<<<NH2_BLOCKS, 256, 0, stream>>>(logits, labels, keys, histg, n);
  // 2) merge per-block hists
  k_merge<<<(L1_BINS / 2 + 255) / 256, 256, 0, stream>>>(histg, merged, NH2_BLOCKS);
  // 3) select L1 bucket (13 bits) for each of 32 ranks
  k_select<<<32, 64, 0, stream>>>(merged, selp, selr, vp, L1_BINS, 0, 0, 0, 1, rk);
  // 4) refine low 9 bits
  k_refine<<<NH2_BLOCKS, 256, 0, stream>>>(keys, selp, hist2, n);
  k_select<<<32, 64, 0, stream>>>(hist2, selp, selr, vp, L2_BINS, 1, 9, 1, 0, rk);
  // 5) binning accumulation (edges computed in-kernel from final keys)
  k_bin<<<NBIN_BLOCKS, 256, 0, stream>>>(keys, vp, part, n, fr);
  // 6) final reduce + gaps mean
  k_final<<<1, 64, 0, stream>>>(part, out);

  (void)n_in; (void)out_size; (void)ws_size;
}